// Round 15
// baseline (537.055 us; speedup 1.0000x reference)
//
#include <hip/hip_runtime.h>

#define NN 50000
#define EE 800000
#define EPN 850000   // EE + NN (self loops appended)

typedef __attribute__((ext_vector_type(8))) short bf16x8;
typedef __attribute__((ext_vector_type(4))) float f32x4;
typedef unsigned short ushort_t;

// ---------- helpers ----------
__device__ __forceinline__ float eluf(float v) { return v > 0.f ? v : expm1f(v); }
__device__ __forceinline__ unsigned short f2bf(float f) {
  unsigned u = __float_as_uint(f);
  unsigned r = (u + 0x7FFFu + ((u >> 16) & 1u)) >> 16;
  return (unsigned short)r;
}
__device__ __forceinline__ float bf2f(unsigned short b) {
  return __uint_as_float(((unsigned)b) << 16);
}
__device__ __forceinline__ void unpack8(uint4 u, float* o) {
  o[0] = __uint_as_float(u.x << 16); o[1] = __uint_as_float(u.x & 0xFFFF0000u);
  o[2] = __uint_as_float(u.y << 16); o[3] = __uint_as_float(u.y & 0xFFFF0000u);
  o[4] = __uint_as_float(u.z << 16); o[5] = __uint_as_float(u.z & 0xFFFF0000u);
  o[6] = __uint_as_float(u.w << 16); o[7] = __uint_as_float(u.w & 0xFFFF0000u);
}
__device__ __forceinline__ void gload_lds16(const ushort_t* g, ushort_t* l) {
  __builtin_amdgcn_global_load_lds((const __attribute__((address_space(1))) void*)g,
                                   (__attribute__((address_space(3))) void*)l, 16, 0, 0);
}

// ---------- W1 pre-convert ----------
__global__ __launch_bounds__(256) void conv_w1(const float* __restrict__ W,
                                               ushort_t* __restrict__ Wc) {
  int idx = blockIdx.x * 256 + threadIdx.x;
  if (idx >= 256 * 1024) return;
  int col = idx >> 10, rem = idx & 1023;
  int kb = rem >> 6, j = rem & 63;
  int sel = j >> 5, k = j & 31;
  int gk = kb * 32 + k;
  float v = W[(size_t)gk * 256 + col];
  unsigned short h = f2bf(v);
  Wc[idx] = sel ? (ushort_t)f2bf(v - bf2f(h)) : h;
}

// ---------- layer-1 GEMM: 128x128, 8 waves ----------
__global__ __launch_bounds__(512) void gemm1_mfma(const float* __restrict__ A,
                                                  const ushort_t* __restrict__ Wc,
                                                  ushort_t* __restrict__ C16, int M) {
  constexpr int K = 512;
  __shared__ alignas(16) ushort_t Bs[2][128 * 64];
  int tid = threadIdx.x;
  int w = tid >> 6, lane = tid & 63, l15 = lane & 15, l4 = lane >> 4;
  int row0 = blockIdx.y * 128, col0 = blockIdx.x * 128;
  int arow = row0 + w * 16 + l15;
  int arowc = arow < M ? arow : M - 1;
  const float* arp = A + (size_t)arowc * K + l4 * 8;

  int chunk_src = (lane & 7) ^ ((lane >> 3) & 7);
  const ushort_t* wsrc =
      Wc + (size_t)(col0 + w * 16 + (lane >> 3)) * 1024 + chunk_src * 8;
  ushort_t* ldst0 = &Bs[0][(w * 16) * 64];
  ushort_t* ldst1 = &Bs[1][(w * 16) * 64];

  int swz = l15 & 7;
  int roff_h = ((l4 ^ swz) << 3);
  int roff_l = (((l4 | 4) ^ swz) << 3);
  int rbase = l15 * 64;

  f32x4 acc[8];
#pragma unroll
  for (int t = 0; t < 8; ++t) acc[t] = (f32x4){0.f, 0.f, 0.f, 0.f};

#pragma unroll
  for (int q = 0; q < 2; ++q) gload_lds16(wsrc + q * 8192, ldst0 + q * 512);
  float4 pa0c = *(const float4*)(arp);
  float4 pa1c = *(const float4*)(arp + 4);
  float4 pa0n, pa1n;

  for (int k0 = 0; k0 < K; k0 += 32) {
    int kb = k0 >> 5, p = kb & 1;
    __syncthreads();
    if (k0 + 32 < K) {
      ushort_t* dst = (p ? ldst0 : ldst1);
      const ushort_t* src = wsrc + (kb + 1) * 64;
#pragma unroll
      for (int q = 0; q < 2; ++q) gload_lds16(src + q * 8192, dst + q * 512);
      pa0n = *(const float4*)(arp + k0 + 32);
      pa1n = *(const float4*)(arp + k0 + 36);
    }
    bf16x8 ah, al;
    {
      float v[8] = {pa0c.x, pa0c.y, pa0c.z, pa0c.w, pa1c.x, pa1c.y, pa1c.z, pa1c.w};
#pragma unroll
      for (int i = 0; i < 8; ++i) {
        unsigned short h = f2bf(v[i]);
        ah[i] = (short)h;
        al[i] = (short)f2bf(v[i] - bf2f(h));
      }
    }
    const ushort_t* bp = &Bs[p][rbase];
#pragma unroll
    for (int t = 0; t < 8; ++t) {
      bf16x8 b_h = *(const bf16x8*)&bp[t * 1024 + roff_h];
      bf16x8 b_l = *(const bf16x8*)&bp[t * 1024 + roff_l];
      acc[t] = __builtin_amdgcn_mfma_f32_16x16x32_bf16(ah, b_h, acc[t], 0, 0, 0);
      acc[t] = __builtin_amdgcn_mfma_f32_16x16x32_bf16(ah, b_l, acc[t], 0, 0, 0);
      acc[t] = __builtin_amdgcn_mfma_f32_16x16x32_bf16(al, b_h, acc[t], 0, 0, 0);
    }
    pa0c = pa0n; pa1c = pa1n;
  }
#pragma unroll
  for (int t = 0; t < 8; ++t) {
#pragma unroll
    for (int r = 0; r < 4; ++r) {
      int grow = row0 + w * 16 + l4 * 4 + r;
      if (grow < M) C16[(size_t)grow * 256 + col0 + t * 16 + l15] = f2bf(acc[t][r]);
    }
  }
}

// ---------- MFMA bf16x3 GEMM (layers 2,3) ----------
template <int NT>
__global__ __launch_bounds__(256) void gemm_mfma(const float* __restrict__ A,
                                                 const float* __restrict__ B,
                                                 ushort_t* __restrict__ C16,
                                                 int M, int N, int K) {
  __shared__ unsigned short Ah[64 * 40], Al[64 * 40];
  __shared__ unsigned short Bh[NT * 16 * 40], Bl[NT * 16 * 40];
  int tid = threadIdx.x;
  int wave = tid >> 6, lane = tid & 63;
  int l15 = lane & 15, l4 = lane >> 4;
  int row0 = blockIdx.y * 64, col0 = blockIdx.x * (NT * 16);

  f32x4 acc[NT];
#pragma unroll
  for (int t = 0; t < NT; ++t) acc[t] = (f32x4){0.f, 0.f, 0.f, 0.f};

  int ar = tid >> 2;
  int ak = (tid & 3) * 8;
  constexpr int TPC = 256 / (NT * 16);
  constexpr int NK = 32 / TPC;
  int bc = tid / TPC;
  int bk = (tid % TPC) * NK;

  for (int k0 = 0; k0 < K; k0 += 32) {
    {
      float v[8];
      int grow = row0 + ar;
      if (grow < M) {
        float4 q0 = *(const float4*)&A[(size_t)grow * K + k0 + ak];
        float4 q1 = *(const float4*)&A[(size_t)grow * K + k0 + ak + 4];
        v[0] = q0.x; v[1] = q0.y; v[2] = q0.z; v[3] = q0.w;
        v[4] = q1.x; v[5] = q1.y; v[6] = q1.z; v[7] = q1.w;
      } else {
#pragma unroll
        for (int i = 0; i < 8; ++i) v[i] = 0.f;
      }
      bf16x8 hv, lv;
#pragma unroll
      for (int i = 0; i < 8; ++i) {
        unsigned short h = f2bf(v[i]);
        hv[i] = (short)h;
        lv[i] = (short)f2bf(v[i] - bf2f(h));
      }
      *(bf16x8*)&Ah[ar * 40 + ak] = hv;
      *(bf16x8*)&Al[ar * 40 + ak] = lv;
    }
    {
#pragma unroll
      for (int i = 0; i < NK; ++i) {
        float v = B[(size_t)(k0 + bk + i) * N + col0 + bc];
        unsigned short h = f2bf(v);
        Bh[bc * 40 + bk + i] = h;
        Bl[bc * 40 + bk + i] = f2bf(v - bf2f(h));
      }
    }
    __syncthreads();
    bf16x8 a_h = *(const bf16x8*)&Ah[(wave * 16 + l15) * 40 + l4 * 8];
    bf16x8 a_l = *(const bf16x8*)&Al[(wave * 16 + l15) * 40 + l4 * 8];
#pragma unroll
    for (int t = 0; t < NT; ++t) {
      bf16x8 b_h = *(const bf16x8*)&Bh[(t * 16 + l15) * 40 + l4 * 8];
      bf16x8 b_l = *(const bf16x8*)&Bl[(t * 16 + l15) * 40 + l4 * 8];
      acc[t] = __builtin_amdgcn_mfma_f32_16x16x32_bf16(a_h, b_h, acc[t], 0, 0, 0);
      acc[t] = __builtin_amdgcn_mfma_f32_16x16x32_bf16(a_h, b_l, acc[t], 0, 0, 0);
      acc[t] = __builtin_amdgcn_mfma_f32_16x16x32_bf16(a_l, b_h, acc[t], 0, 0, 0);
    }
    __syncthreads();
  }
#pragma unroll
  for (int t = 0; t < NT; ++t) {
#pragma unroll
    for (int r = 0; r < 4; ++r) {
      int grow = row0 + wave * 16 + l4 * 4 + r;
      if (grow < M) C16[(size_t)grow * N + col0 + t * 16 + l15] = f2bf(acc[t][r]);
    }
  }
}

// ---------- aux head device body (both GEMMs via MFMA, bf16 xt) ----------
template <int C>
__device__ __forceinline__ void aux_body(char* smem, int bid,
                                         const ushort_t* __restrict__ xt16,
                                         const float* __restrict__ Wh1,
                                         const float* __restrict__ bh1,
                                         const float* __restrict__ Wh2,
                                         const float* __restrict__ bh2,
                                         float* __restrict__ hout, float scale) {
  constexpr int KS = C / 32;
  constexpr int LDB = C + 8;
  ushort_t* w2h = (ushort_t*)smem;                  // 32*72
  ushort_t* w2l = w2h + 32 * 72;                    // 32*72
  ushort_t* BhS = (ushort_t*)(smem + 9216);
  ushort_t* BlS = BhS + 64 * LDB;
  ushort_t* hidh = (ushort_t*)(smem + 9216);        // aliases BhS
  ushort_t* hidl = hidh + 64 * 72;

  int tid = threadIdx.x;
  for (int i = tid; i < C * 64; i += 256) {
    int k = i >> 6, col = i & 63;
    float v = Wh1[i];
    unsigned short h = f2bf(v);
    BhS[col * LDB + k] = h;
    BlS[col * LDB + k] = f2bf(v - bf2f(h));
  }
  for (int i = tid; i < 64 * 32; i += 256) {
    int k = i >> 5, col = i & 31;
    float v = Wh2[i];
    unsigned short h = f2bf(v);
    w2h[col * 72 + k] = h;
    w2l[col * 72 + k] = f2bf(v - bf2f(h));
  }
  __syncthreads();

  int w = tid >> 6, lane = tid & 63, l15 = lane & 15, l4 = lane >> 4;
  int gr = bid * 64 + w * 16 + l15;
  const int M2 = 2 * NN;

  f32x4 acc[4];
#pragma unroll
  for (int t = 0; t < 4; ++t) acc[t] = (f32x4){0.f, 0.f, 0.f, 0.f};

#pragma unroll
  for (int ks = 0; ks < KS; ++ks) {
    bf16x8 ah;
    if (gr < M2) {
      ah = *(const bf16x8*)(xt16 + (size_t)gr * C + ks * 32 + l4 * 8);
    } else {
      ah = (bf16x8){0, 0, 0, 0, 0, 0, 0, 0};
    }
#pragma unroll
    for (int t = 0; t < 4; ++t) {
      bf16x8 b_h = *(const bf16x8*)&BhS[(t * 16 + l15) * LDB + ks * 32 + l4 * 8];
      bf16x8 b_l = *(const bf16x8*)&BlS[(t * 16 + l15) * LDB + ks * 32 + l4 * 8];
      acc[t] = __builtin_amdgcn_mfma_f32_16x16x32_bf16(ah, b_h, acc[t], 0, 0, 0);
      acc[t] = __builtin_amdgcn_mfma_f32_16x16x32_bf16(ah, b_l, acc[t], 0, 0, 0);
    }
  }
  __syncthreads();
#pragma unroll
  for (int t = 0; t < 4; ++t) {
    float bb = bh1[t * 16 + l15];
#pragma unroll
    for (int r = 0; r < 4; ++r) {
      float h = eluf(acc[t][r] + bb);
      unsigned short hh = f2bf(h);
      int row = w * 16 + l4 * 4 + r, col = t * 16 + l15;
      hidh[row * 72 + col] = hh;
      hidl[row * 72 + col] = f2bf(h - bf2f(hh));
    }
  }
  __syncthreads();
  f32x4 acc2[2];
  acc2[0] = (f32x4){0.f, 0.f, 0.f, 0.f};
  acc2[1] = acc2[0];
#pragma unroll
  for (int ks = 0; ks < 2; ++ks) {
    bf16x8 ah = *(const bf16x8*)&hidh[(w * 16 + l15) * 72 + ks * 32 + l4 * 8];
    bf16x8 al = *(const bf16x8*)&hidl[(w * 16 + l15) * 72 + ks * 32 + l4 * 8];
#pragma unroll
    for (int t2 = 0; t2 < 2; ++t2) {
      bf16x8 b_h = *(const bf16x8*)&w2h[(t2 * 16 + l15) * 72 + ks * 32 + l4 * 8];
      bf16x8 b_l = *(const bf16x8*)&w2l[(t2 * 16 + l15) * 72 + ks * 32 + l4 * 8];
      acc2[t2] = __builtin_amdgcn_mfma_f32_16x16x32_bf16(ah, b_h, acc2[t2], 0, 0, 0);
      acc2[t2] = __builtin_amdgcn_mfma_f32_16x16x32_bf16(ah, b_l, acc2[t2], 0, 0, 0);
      acc2[t2] = __builtin_amdgcn_mfma_f32_16x16x32_bf16(al, b_h, acc2[t2], 0, 0, 0);
    }
  }
#pragma unroll
  for (int t2 = 0; t2 < 2; ++t2) {
    int col = t2 * 16 + l15;
    float bb = bh2[col];
#pragma unroll
    for (int r = 0; r < 4; ++r) {
      int gr2 = bid * 64 + w * 16 + l4 * 4 + r;
      if (gr2 < M2)
        hout[(size_t)(gr2 >> 1) * 64 + (gr2 & 1) * 32 + col] = (acc2[t2][r] + bb) * scale;
    }
  }
}

// ---------- gat256 device body (edge-pair, per-head softmax, defer-max, LN+ELU) ----------
__device__ __forceinline__ void gat256_body(int bid, const ushort_t* __restrict__ xt16,
                                            const int* __restrict__ srcs,
                                            const int* __restrict__ rowptr,
                                            float* __restrict__ outb,
                                            const float* __restrict__ g,
                                            const float* __restrict__ b) {
  int node = (int)(((size_t)bid * 256 + threadIdx.x) >> 6);
  int lane = threadIdx.x & 63;
  if (node >= NN) return;
  int l32 = lane & 31, half = lane >> 5;
  int start = rowptr[node], end = rowptr[node + 1];
  float dv[8];
  unpack8(*(const uint4*)(xt16 + (size_t)node * 256 + l32 * 8), dv);
  float m = -3e38f, s_h = 0.f;
  float acc[8] = {0.f, 0.f, 0.f, 0.f, 0.f, 0.f, 0.f, 0.f};

  int i = start;
  for (; i + 8 <= end; i += 8) {
    int sj[4];
    float sv[4][8];
    float p[4];
#pragma unroll
    for (int q = 0; q < 4; ++q) sj[q] = srcs[i + q * 2 + half];
#pragma unroll
    for (int q = 0; q < 4; ++q)
      unpack8(*(const uint4*)(xt16 + (size_t)sj[q] * 256 + l32 * 8), sv[q]);
#pragma unroll
    for (int q = 0; q < 4; ++q) {
      float p_ = 0.f;
#pragma unroll
      for (int k = 0; k < 8; ++k) p_ = fmaf(sv[q][k], dv[k], p_);
      p_ += __shfl_xor(p_, 1); p_ += __shfl_xor(p_, 2);
      p_ += __shfl_xor(p_, 4); p_ += __shfl_xor(p_, 8);
      p[q] = p_ * 0.08838834764831843f;  // 1/sqrt(128)
    }
    float pm = fmaxf(fmaxf(p[0], p[1]), fmaxf(p[2], p[3]));
    if (__any(pm > m + 8.f)) {
#pragma unroll
      for (int q = 0; q < 4; ++q) {
        float pb = fmaxf(p[q], __shfl_xor(p[q], 32));
        float mn = fmaxf(m, pb);
        float scf = __expf(m - mn), w = __expf(p[q] - mn);
        s_h = s_h * scf + w;
#pragma unroll
        for (int k = 0; k < 8; ++k) acc[k] = fmaf(w, sv[q][k], acc[k] * scf);
        m = mn;
      }
    } else {
#pragma unroll
      for (int q = 0; q < 4; ++q) {
        float w = __expf(p[q] - m);
        s_h += w;
#pragma unroll
        for (int k = 0; k < 8; ++k) acc[k] = fmaf(w, sv[q][k], acc[k]);
      }
    }
  }
  for (; i < end; i += 2) {
    bool valid = (i + half) < end;
    int sj = srcs[valid ? i + half : i];
    float sv[8];
    unpack8(*(const uint4*)(xt16 + (size_t)sj * 256 + l32 * 8), sv);
    float p_ = 0.f;
#pragma unroll
    for (int k = 0; k < 8; ++k) p_ = fmaf(sv[k], dv[k], p_);
    p_ += __shfl_xor(p_, 1); p_ += __shfl_xor(p_, 2);
    p_ += __shfl_xor(p_, 4); p_ += __shfl_xor(p_, 8);
    p_ *= 0.08838834764831843f;
    if (!valid) p_ = -3e38f;
    float pb = fmaxf(p_, __shfl_xor(p_, 32));
    float mn = fmaxf(m, pb);
    float scf = __expf(m - mn);
    float w = valid ? __expf(p_ - mn) : 0.f;
    s_h = s_h * scf + w;
#pragma unroll
    for (int k = 0; k < 8; ++k) acc[k] = fmaf(w, sv[k], acc[k] * scf);
    m = mn;
  }
  float s = s_h + __shfl_xor(s_h, 32);
#pragma unroll
  for (int k = 0; k < 8; ++k) acc[k] += __shfl_xor(acc[k], 32);
  float inv = 1.f / (s + 1e-16f);
  float v[8];
#pragma unroll
  for (int k = 0; k < 8; ++k) v[k] = acc[k] * inv;
  float sum = 0.f;
#pragma unroll
  for (int k = 0; k < 8; ++k) sum += v[k];
  sum += __shfl_xor(sum, 1); sum += __shfl_xor(sum, 2); sum += __shfl_xor(sum, 4);
  sum += __shfl_xor(sum, 8); sum += __shfl_xor(sum, 16);
  float mean = sum * (1.f / 256.f);
  float q = 0.f;
#pragma unroll
  for (int k = 0; k < 8; ++k) { v[k] -= mean; q = fmaf(v[k], v[k], q); }
  q += __shfl_xor(q, 1); q += __shfl_xor(q, 2); q += __shfl_xor(q, 4);
  q += __shfl_xor(q, 8); q += __shfl_xor(q, 16);
  float rstd = rsqrtf(q * (1.f / 256.f) + 1e-5f);
  if (half == 0) {
    float4 ga = *(const float4*)&g[l32 * 8], gb = *(const float4*)&g[l32 * 8 + 4];
    float4 ba = *(const float4*)&b[l32 * 8], bb = *(const float4*)&b[l32 * 8 + 4];
    float4 r0, r1;
    r0.x = eluf(v[0] * rstd * ga.x + ba.x); r0.y = eluf(v[1] * rstd * ga.y + ba.y);
    r0.z = eluf(v[2] * rstd * ga.z + ba.z); r0.w = eluf(v[3] * rstd * ga.w + ba.w);
    r1.x = eluf(v[4] * rstd * gb.x + bb.x); r1.y = eluf(v[5] * rstd * gb.y + bb.y);
    r1.z = eluf(v[6] * rstd * gb.z + bb.z); r1.w = eluf(v[7] * rstd * gb.w + bb.w);
    *(float4*)(outb + (size_t)node * 256 + l32 * 8) = r0;
    *(float4*)(outb + (size_t)node * 256 + l32 * 8 + 4) = r1;
  }
}

// ---------- gat64 device body (transposed batch, streamlined phase 2) ----------
template <int MODE>
__device__ __forceinline__ void gat64_body(float (*wbuf)[64], int bid,
                                           const ushort_t* __restrict__ xt16,
                                           const int* __restrict__ srcs,
                                           const int* __restrict__ eids,
                                           const int* __restrict__ rowptr,
                                           float* __restrict__ outf,
                                           float* __restrict__ logit_out,
                                           float* __restrict__ mbuf,
                                           float* __restrict__ sbuf,
                                           const float* __restrict__ g,
                                           const float* __restrict__ b) {
  int wv = threadIdx.x >> 6;
  int node = (int)(((size_t)bid * 256 + threadIdx.x) >> 6);
  int lane = threadIdx.x & 63;
  if (node >= NN) return;
  int l32 = lane & 31, half = lane >> 5;
  int start = rowptr[node], end = rowptr[node + 1];
  float dv[32];
  {
    const ushort_t* dp = xt16 + (size_t)node * 64 + half * 32;
    unpack8(*(const uint4*)(dp), dv);
    unpack8(*(const uint4*)(dp + 8), dv + 8);
    unpack8(*(const uint4*)(dp + 16), dv + 16);
    unpack8(*(const uint4*)(dp + 24), dv + 24);
  }
  float m = -3e38f, s = 0.f, acc = 0.f;

  for (int base = start; base < end; base += 32) {
    int cnt = end - base;
    cnt = cnt > 32 ? 32 : cnt;
    int sidx = srcs[base + (l32 < cnt ? l32 : 0)];
    float sv[32];
    {
      const ushort_t* sp = xt16 + (size_t)sidx * 64 + half * 32;
      unpack8(*(const uint4*)(sp), sv);
      unpack8(*(const uint4*)(sp + 8), sv + 8);
      unpack8(*(const uint4*)(sp + 16), sv + 16);
      unpack8(*(const uint4*)(sp + 24), sv + 24);
    }
    float p = 0.f;
#pragma unroll
    for (int k = 0; k < 32; ++k) p = fmaf(sv[k], dv[k], p);
    p *= 0.17677669529663687f;  // 1/sqrt(32)
    if (MODE == 1) {
      if (l32 < cnt) logit_out[(size_t)eids[base + l32] * 2 + half] = p;
    }
    if (l32 >= cnt) p = -3e38f;
    float bm = p;
    bm = fmaxf(bm, __shfl_xor(bm, 1));
    bm = fmaxf(bm, __shfl_xor(bm, 2));
    bm = fmaxf(bm, __shfl_xor(bm, 4));
    bm = fmaxf(bm, __shfl_xor(bm, 8));
    bm = fmaxf(bm, __shfl_xor(bm, 16));
    float mn = fmaxf(m, bm);
    float scf = __expf(m - mn);
    float w = (l32 < cnt) ? __expf(p - mn) : 0.f;
    wbuf[wv][(half << 5) + l32] = w;
    float bs = w;
    bs += __shfl_xor(bs, 1);
    bs += __shfl_xor(bs, 2);
    bs += __shfl_xor(bs, 4);
    bs += __shfl_xor(bs, 8);
    bs += __shfl_xor(bs, 16);
    s = s * scf + bs;
    acc *= scf;
    m = mn;
    int nb4 = cnt & ~3;
    const float* wp = &wbuf[wv][(half << 5)];
    for (int e = 0; e < nb4; e += 4) {
      float4 w4 = *(const float4*)(wp + e);
      int s0 = srcs[base + e + 0];
      int s1 = srcs[base + e + 1];
      int s2 = srcs[base + e + 2];
      int s3 = srcs[base + e + 3];
      acc = fmaf(w4.x, bf2f(xt16[(size_t)s0 * 64 + lane]), acc);
      acc = fmaf(w4.y, bf2f(xt16[(size_t)s1 * 64 + lane]), acc);
      acc = fmaf(w4.z, bf2f(xt16[(size_t)s2 * 64 + lane]), acc);
      acc = fmaf(w4.w, bf2f(xt16[(size_t)s3 * 64 + lane]), acc);
    }
    for (int e = nb4; e < cnt; ++e) {
      float wq = wp[e];
      int sj = srcs[base + e];
      acc = fmaf(wq, bf2f(xt16[(size_t)sj * 64 + lane]), acc);
    }
  }
  float inv = 1.f / (s + 1e-16f);
  float v = acc * inv;
  if (MODE == 0) {
    float sum = v;
#pragma unroll
    for (int o = 1; o < 64; o <<= 1) sum += __shfl_xor(sum, o);
    float mean = sum * (1.f / 64.f);
    float dvv = v - mean;
    float q = dvv * dvv;
#pragma unroll
    for (int o = 1; o < 64; o <<= 1) q += __shfl_xor(q, o);
    float rstd = rsqrtf(q * (1.f / 64.f) + 1e-5f);
    outf[(size_t)node * 64 + lane] = eluf(dvv * rstd * g[lane] + b[lane]);
  } else {
    if (l32 == 0) {
      mbuf[(size_t)node * 2 + half] = m;
      sbuf[(size_t)node * 2 + half] = s;
    }
    float t = __shfl_xor(v, 32);
    float y = 0.5f * (v + t);
    float sum = y;
#pragma unroll
    for (int o = 1; o < 32; o <<= 1) sum += __shfl_xor(sum, o);
    float mean = sum * (1.f / 32.f);
    float dy = y - mean;
    float q = dy * dy;
#pragma unroll
    for (int o = 1; o < 32; o <<= 1) q += __shfl_xor(q, o);
    float rstd = rsqrtf(q * (1.f / 32.f) + 1e-5f);
    if (half == 0) outf[(size_t)node * 32 + l32] = dy * rstd * g[l32] + b[l32];
  }
}

// ---------- fused per-layer kernels: 1 aux block per 8 gat blocks (period 9) ----------
// grid = 9 * A_AUX; pos 0 of each group = aux block, else gat block (guarded).
#define A_AUX 1563   // (2*NN + 63) / 64
#define G_GAT 12500  // (NN*64 + 255) / 256

__global__ __launch_bounds__(256) void fused_l1(const ushort_t* __restrict__ xt16,
                                                const float* __restrict__ Wh1,
                                                const float* __restrict__ bh1,
                                                const float* __restrict__ Wh2,
                                                const float* __restrict__ bh2,
                                                float* __restrict__ hout,
                                                const int* __restrict__ srcs,
                                                const int* __restrict__ rowptr,
                                                float* __restrict__ outb,
                                                const float* __restrict__ g,
                                                const float* __restrict__ b) {
  __shared__ alignas(16) char smem[46080];
  int k = blockIdx.x, grp = k / 9, pos = k - grp * 9;
  if (pos == 0) {
    aux_body<128>(smem, grp, xt16, Wh1, bh1, Wh2, bh2, hout, 1.0f);
  } else {
    int gid = grp * 8 + pos - 1;
    if (gid < G_GAT) gat256_body(gid, xt16, srcs, rowptr, outb, g, b);
  }
}

template <int MODE>
__global__ __launch_bounds__(256) void fused_l23(const ushort_t* __restrict__ xt16,
                                                 const float* __restrict__ Wh1,
                                                 const float* __restrict__ bh1,
                                                 const float* __restrict__ Wh2,
                                                 const float* __restrict__ bh2,
                                                 float* __restrict__ hout, float scale,
                                                 const int* __restrict__ srcs,
                                                 const int* __restrict__ eids,
                                                 const int* __restrict__ rowptr,
                                                 float* __restrict__ outf,
                                                 float* __restrict__ logit_out,
                                                 float* __restrict__ mbuf,
                                                 float* __restrict__ sbuf,
                                                 const float* __restrict__ g,
                                                 const float* __restrict__ b) {
  __shared__ alignas(16) char smem[46080];
  int k = blockIdx.x, grp = k / 9, pos = k - grp * 9;
  if (pos == 0) {
    aux_body<32>(smem, grp, xt16, Wh1, bh1, Wh2, bh2, hout, scale);
  } else {
    int gid = grp * 8 + pos - 1;
    if (gid < G_GAT)
      gat64_body<MODE>((float(*)[64])smem, gid, xt16, srcs, eids, rowptr, outf,
                       logit_out, mbuf, sbuf, g, b);
  }
}

// ---------- CSR build ----------
__global__ __launch_bounds__(256) void hist_kernel(const int* __restrict__ ei,
                                                   int* __restrict__ cnt) {
  int e = blockIdx.x * 256 + threadIdx.x;
  if (e >= EPN) return;
  int d = (e < EE) ? ei[EE + e] : e - EE;
  atomicAdd(&cnt[d], 1);
}

__global__ __launch_bounds__(1024) void scan_blocks(const int* __restrict__ cnt,
                                                    int* __restrict__ tmp,
                                                    int* __restrict__ bsum) {
  __shared__ int lds[1024];
  int t = threadIdx.x, idx = blockIdx.x * 1024 + t;
  int v = (idx < NN) ? cnt[idx] : 0;
  lds[t] = v;
  __syncthreads();
  for (int off = 1; off < 1024; off <<= 1) {
    int add = (t >= off) ? lds[t - off] : 0;
    __syncthreads();
    lds[t] += add;
    __syncthreads();
  }
  if (idx < NN) tmp[idx] = lds[t];
  if (t == 1023) bsum[blockIdx.x] = lds[t];
}

__global__ __launch_bounds__(64) void scan_bsum(int* __restrict__ bsum, int nb) {
  int t = threadIdx.x;
  int v = (t < nb) ? bsum[t] : 0;
#pragma unroll
  for (int off = 1; off < 64; off <<= 1) {
    int u = __shfl_up(v, off);
    if (t >= off) v += u;
  }
  if (t < nb) bsum[t] = v;
}

__global__ __launch_bounds__(256) void scan_final(const int* __restrict__ cnt,
                                                  const int* __restrict__ tmp,
                                                  const int* __restrict__ bsum,
                                                  int* __restrict__ rowptr,
                                                  int* __restrict__ fill) {
  int idx = blockIdx.x * 256 + threadIdx.x;
  if (idx >= NN) return;
  int b = idx >> 10;
  int off = (b > 0) ? bsum[b - 1] : 0;
  int inc = tmp[idx] + off;
  rowptr[idx + 1] = inc;
  fill[idx] = inc - cnt[idx];
  if (idx == 0) rowptr[0] = 0;
}

__global__ __launch_bounds__(256) void scatter_kernel(const int* __restrict__ ei,
                                                      int* __restrict__ fill,
                                                      int* __restrict__ eids,
                                                      int* __restrict__ srcs) {
  int e = blockIdx.x * 256 + threadIdx.x;
  if (e >= EPN) return;
  int d, s;
  if (e < EE) { d = ei[EE + e]; s = ei[e]; } else { d = s = e - EE; }
  int pos = atomicAdd(&fill[d], 1);
  eids[pos] = e;
  srcs[pos] = s;
}

// ---------- alpha fix-up ----------
__global__ __launch_bounds__(256) void alpha_fix(float* __restrict__ al,
                                                 const int* __restrict__ ei,
                                                 const float* __restrict__ mbuf,
                                                 const float* __restrict__ sbuf) {
  size_t i = blockIdx.x * (size_t)blockDim.x + threadIdx.x;
  if (i >= (size_t)EPN * 2) return;
  int e = (int)(i >> 1), h = (int)(i & 1);
  int d = (e < EE) ? ei[EE + e] : e - EE;
  al[i] = expf(al[i] - mbuf[(size_t)d * 2 + h]) / (sbuf[(size_t)d * 2 + h] + 1e-16f);
}

extern "C" void kernel_launch(void* const* d_in, const int* in_sizes, int n_in,
                              void* d_out, int out_size, void* d_ws, size_t ws_size,
                              hipStream_t stream) {
  const float* x    = (const float*)d_in[0];
  const int*   ei   = (const int*)d_in[1];
  const float* W1   = (const float*)d_in[2];
  const float* Wh1a = (const float*)d_in[3];
  const float* bh1a = (const float*)d_in[4];
  const float* Wh2a = (const float*)d_in[5];
  const float* bh2a = (const float*)d_in[6];
  const float* g1   = (const float*)d_in[7];
  const float* b1   = (const float*)d_in[8];
  const float* W2   = (const float*)d_in[9];
  const float* Wh1b = (const float*)d_in[10];
  const float* bh1b = (const float*)d_in[11];
  const float* Wh2b = (const float*)d_in[12];
  const float* bh2b = (const float*)d_in[13];
  const float* g2   = (const float*)d_in[14];
  const float* b2   = (const float*)d_in[15];
  const float* W3   = (const float*)d_in[16];
  const float* Wh1c = (const float*)d_in[17];
  const float* bh1c = (const float*)d_in[18];
  const float* Wh2c = (const float*)d_in[19];
  const float* bh2c = (const float*)d_in[20];
  const float* g3   = (const float*)d_in[21];
  const float* b3   = (const float*)d_in[22];

  float* out  = (float*)d_out;
  float* o_x3 = out;                           // N*32
  float* o_h1 = out + (size_t)NN * 32;         // N*64
  float* o_h2 = o_h1 + (size_t)NN * 64;        // N*64
  float* o_h3 = o_h2 + (size_t)NN * 64;        // N*64
  float* o_al = o_h3 + (size_t)NN * 64;        // EPN*2 (logits then alpha)

  float* ws  = (float*)d_ws;
  float* A   = ws;                             // N*256 f32 slot (bf16 xt)
  float* Bb  = ws + (size_t)NN * 256;          // N*256 f32 (x1/x2)
  int* cnt    = (int*)(Bb + (size_t)NN * 256); // NN
  int* rowptr = cnt + NN;                      // NN+1
  int* fill   = rowptr + NN + 1;               // NN
  int* eids   = fill + NN;                     // EPN
  int* srcs   = eids + EPN;                    // EPN
  int* tmp    = srcs + EPN;                    // NN
  int* bsum   = tmp + NN;                      // 64
  float* mbuf = (float*)(bsum + 64);           // NN*2
  float* sbuf = mbuf + (size_t)NN * 2;         // NN*2
  ushort_t* W1c = (ushort_t*)(sbuf + (size_t)NN * 2);  // 256*1024 ushorts
  ushort_t* A16 = (ushort_t*)A;                // xt buffers (bf16)

  dim3 blk(256);
  int gEdges = (EPN + 255) / 256;
  int gRows = (NN + 63) / 64;
  int gRows128 = (NN + 127) / 128;
  int gPairs = (int)(((size_t)EPN * 2 + 255) / 256);
  int nbScan = (NN + 1023) / 1024;
  int gFused = 9 * A_AUX;

  // ---------------- CSR by dst + W1 preconversion ----------------
  conv_w1<<<1024, blk, 0, stream>>>(W1, W1c);
  hipMemsetAsync(cnt, 0, (size_t)NN * 4, stream);
  hist_kernel<<<gEdges, blk, 0, stream>>>(ei, cnt);
  scan_blocks<<<nbScan, 1024, 0, stream>>>(cnt, tmp, bsum);
  scan_bsum<<<1, 64, 0, stream>>>(bsum, nbScan);
  scan_final<<<(NN + 255) / 256, blk, 0, stream>>>(cnt, tmp, bsum, rowptr, fill);
  scatter_kernel<<<gEdges, blk, 0, stream>>>(ei, fill, eids, srcs);

  // ---------------- Layer 1: 512 -> 2x128 (concat) ----------------
  gemm1_mfma<<<dim3(2, gRows128), 512, 0, stream>>>(x, W1c, A16, NN);
  fused_l1<<<gFused, blk, 0, stream>>>(A16, Wh1a, bh1a, Wh2a, bh2a, o_h1,
                                       srcs, rowptr, Bb, g1, b1);

  // ---------------- Layer 2: 256 -> 2x32 (concat) ----------------
  gemm_mfma<4><<<dim3(1, gRows), blk, 0, stream>>>(Bb, W2, A16, NN, 64, 256);
  fused_l23<0><<<gFused, blk, 0, stream>>>(A16, Wh1b, bh1b, Wh2b, bh2b, o_h2, 0.5f,
                                           srcs, nullptr, rowptr, Bb, nullptr,
                                           nullptr, nullptr, g2, b2);

  // ---------------- Layer 3: 64 -> 2x32 (mean) ----------------
  gemm_mfma<4><<<dim3(1, gRows), blk, 0, stream>>>(Bb, W3, A16, NN, 64, 64);
  fused_l23<1><<<gFused, blk, 0, stream>>>(A16, Wh1c, bh1c, Wh2c, bh2c, o_h3, 1.0f,
                                           srcs, eids, rowptr, o_x3, o_al,
                                           mbuf, sbuf, g3, b3);
  alpha_fix<<<gPairs, blk, 0, stream>>>(o_al, ei, mbuf, sbuf);
}

// Round 16
// 475.503 us; speedup vs baseline: 1.1294x; 1.1294x over previous
//
#include <hip/hip_runtime.h>

#define NN 50000
#define EE 800000
#define EPN 850000   // EE + NN (self loops appended)

typedef __attribute__((ext_vector_type(8))) short bf16x8;
typedef __attribute__((ext_vector_type(4))) float f32x4;
typedef unsigned short ushort_t;

// ---------- helpers ----------
__device__ __forceinline__ float eluf(float v) { return v > 0.f ? v : expm1f(v); }
__device__ __forceinline__ unsigned short f2bf(float f) {
  unsigned u = __float_as_uint(f);
  unsigned r = (u + 0x7FFFu + ((u >> 16) & 1u)) >> 16;
  return (unsigned short)r;
}
__device__ __forceinline__ float bf2f(unsigned short b) {
  return __uint_as_float(((unsigned)b) << 16);
}
__device__ __forceinline__ void unpack8(uint4 u, float* o) {
  o[0] = __uint_as_float(u.x << 16); o[1] = __uint_as_float(u.x & 0xFFFF0000u);
  o[2] = __uint_as_float(u.y << 16); o[3] = __uint_as_float(u.y & 0xFFFF0000u);
  o[4] = __uint_as_float(u.z << 16); o[5] = __uint_as_float(u.z & 0xFFFF0000u);
  o[6] = __uint_as_float(u.w << 16); o[7] = __uint_as_float(u.w & 0xFFFF0000u);
}
__device__ __forceinline__ void gload_lds16(const ushort_t* g, ushort_t* l) {
  __builtin_amdgcn_global_load_lds((const __attribute__((address_space(1))) void*)g,
                                   (__attribute__((address_space(3))) void*)l, 16, 0, 0);
}

// ---------- W1 pre-convert: W[512,256] f32 -> Wc[col][kb][hi32|lo32] ushort ----------
__global__ __launch_bounds__(256) void conv_w1(const float* __restrict__ W,
                                               ushort_t* __restrict__ Wc) {
  int idx = blockIdx.x * 256 + threadIdx.x;
  if (idx >= 256 * 1024) return;
  int col = idx >> 10, rem = idx & 1023;
  int kb = rem >> 6, j = rem & 63;
  int sel = j >> 5, k = j & 31;
  int gk = kb * 32 + k;
  float v = W[(size_t)gk * 256 + col];
  unsigned short h = f2bf(v);
  Wc[idx] = sel ? (ushort_t)f2bf(v - bf2f(h)) : h;
}

// ---------- layer-1 GEMM: A16[M,256](bf16) = A[M,512] @ W1, bf16x3 internal ----------
// 128x128 per block, 8 waves: 4 blocks/CU = 32 waves, 782 blocks ~3.05/CU.
__global__ __launch_bounds__(512) void gemm1_mfma(const float* __restrict__ A,
                                                  const ushort_t* __restrict__ Wc,
                                                  ushort_t* __restrict__ C16, int M) {
  constexpr int K = 512;
  __shared__ alignas(16) ushort_t Bs[2][128 * 64];
  int tid = threadIdx.x;
  int w = tid >> 6, lane = tid & 63, l15 = lane & 15, l4 = lane >> 4;
  int row0 = blockIdx.y * 128, col0 = blockIdx.x * 128;
  int arow = row0 + w * 16 + l15;
  int arowc = arow < M ? arow : M - 1;
  const float* arp = A + (size_t)arowc * K + l4 * 8;

  int chunk_src = (lane & 7) ^ ((lane >> 3) & 7);
  const ushort_t* wsrc =
      Wc + (size_t)(col0 + w * 16 + (lane >> 3)) * 1024 + chunk_src * 8;
  ushort_t* ldst0 = &Bs[0][(w * 16) * 64];
  ushort_t* ldst1 = &Bs[1][(w * 16) * 64];

  int swz = l15 & 7;
  int roff_h = ((l4 ^ swz) << 3);
  int roff_l = (((l4 | 4) ^ swz) << 3);
  int rbase = l15 * 64;

  f32x4 acc[8];
#pragma unroll
  for (int t = 0; t < 8; ++t) acc[t] = (f32x4){0.f, 0.f, 0.f, 0.f};

#pragma unroll
  for (int q = 0; q < 2; ++q) gload_lds16(wsrc + q * 8192, ldst0 + q * 512);
  float4 pa0c = *(const float4*)(arp);
  float4 pa1c = *(const float4*)(arp + 4);
  float4 pa0n, pa1n;

  for (int k0 = 0; k0 < K; k0 += 32) {
    int kb = k0 >> 5, p = kb & 1;
    __syncthreads();
    if (k0 + 32 < K) {
      ushort_t* dst = (p ? ldst0 : ldst1);
      const ushort_t* src = wsrc + (kb + 1) * 64;
#pragma unroll
      for (int q = 0; q < 2; ++q) gload_lds16(src + q * 8192, dst + q * 512);
      pa0n = *(const float4*)(arp + k0 + 32);
      pa1n = *(const float4*)(arp + k0 + 36);
    }
    bf16x8 ah, al;
    {
      float v[8] = {pa0c.x, pa0c.y, pa0c.z, pa0c.w, pa1c.x, pa1c.y, pa1c.z, pa1c.w};
#pragma unroll
      for (int i = 0; i < 8; ++i) {
        unsigned short h = f2bf(v[i]);
        ah[i] = (short)h;
        al[i] = (short)f2bf(v[i] - bf2f(h));
      }
    }
    const ushort_t* bp = &Bs[p][rbase];
#pragma unroll
    for (int t = 0; t < 8; ++t) {
      bf16x8 b_h = *(const bf16x8*)&bp[t * 1024 + roff_h];
      bf16x8 b_l = *(const bf16x8*)&bp[t * 1024 + roff_l];
      acc[t] = __builtin_amdgcn_mfma_f32_16x16x32_bf16(ah, b_h, acc[t], 0, 0, 0);
      acc[t] = __builtin_amdgcn_mfma_f32_16x16x32_bf16(ah, b_l, acc[t], 0, 0, 0);
      acc[t] = __builtin_amdgcn_mfma_f32_16x16x32_bf16(al, b_h, acc[t], 0, 0, 0);
    }
    pa0c = pa0n; pa1c = pa1n;
  }
#pragma unroll
  for (int t = 0; t < 8; ++t) {
#pragma unroll
    for (int r = 0; r < 4; ++r) {
      int grow = row0 + w * 16 + l4 * 4 + r;
      if (grow < M) C16[(size_t)grow * 256 + col0 + t * 16 + l15] = f2bf(acc[t][r]);
    }
  }
}

// ---------- MFMA bf16x3 GEMM (layers 2,3): C16[M,N](bf16) = A[M,K](f32)@B[K,N](f32) ----------
template <int NT>
__global__ __launch_bounds__(256) void gemm_mfma(const float* __restrict__ A,
                                                 const float* __restrict__ B,
                                                 ushort_t* __restrict__ C16,
                                                 int M, int N, int K) {
  __shared__ unsigned short Ah[64 * 40], Al[64 * 40];
  __shared__ unsigned short Bh[NT * 16 * 40], Bl[NT * 16 * 40];
  int tid = threadIdx.x;
  int wave = tid >> 6, lane = tid & 63;
  int l15 = lane & 15, l4 = lane >> 4;
  int row0 = blockIdx.y * 64, col0 = blockIdx.x * (NT * 16);

  f32x4 acc[NT];
#pragma unroll
  for (int t = 0; t < NT; ++t) acc[t] = (f32x4){0.f, 0.f, 0.f, 0.f};

  int ar = tid >> 2;
  int ak = (tid & 3) * 8;
  constexpr int TPC = 256 / (NT * 16);
  constexpr int NK = 32 / TPC;
  int bc = tid / TPC;
  int bk = (tid % TPC) * NK;

  for (int k0 = 0; k0 < K; k0 += 32) {
    {
      float v[8];
      int grow = row0 + ar;
      if (grow < M) {
        float4 q0 = *(const float4*)&A[(size_t)grow * K + k0 + ak];
        float4 q1 = *(const float4*)&A[(size_t)grow * K + k0 + ak + 4];
        v[0] = q0.x; v[1] = q0.y; v[2] = q0.z; v[3] = q0.w;
        v[4] = q1.x; v[5] = q1.y; v[6] = q1.z; v[7] = q1.w;
      } else {
#pragma unroll
        for (int i = 0; i < 8; ++i) v[i] = 0.f;
      }
      bf16x8 hv, lv;
#pragma unroll
      for (int i = 0; i < 8; ++i) {
        unsigned short h = f2bf(v[i]);
        hv[i] = (short)h;
        lv[i] = (short)f2bf(v[i] - bf2f(h));
      }
      *(bf16x8*)&Ah[ar * 40 + ak] = hv;
      *(bf16x8*)&Al[ar * 40 + ak] = lv;
    }
    {
#pragma unroll
      for (int i = 0; i < NK; ++i) {
        float v = B[(size_t)(k0 + bk + i) * N + col0 + bc];
        unsigned short h = f2bf(v);
        Bh[bc * 40 + bk + i] = h;
        Bl[bc * 40 + bk + i] = f2bf(v - bf2f(h));
      }
    }
    __syncthreads();
    bf16x8 a_h = *(const bf16x8*)&Ah[(wave * 16 + l15) * 40 + l4 * 8];
    bf16x8 a_l = *(const bf16x8*)&Al[(wave * 16 + l15) * 40 + l4 * 8];
#pragma unroll
    for (int t = 0; t < NT; ++t) {
      bf16x8 b_h = *(const bf16x8*)&Bh[(t * 16 + l15) * 40 + l4 * 8];
      bf16x8 b_l = *(const bf16x8*)&Bl[(t * 16 + l15) * 40 + l4 * 8];
      acc[t] = __builtin_amdgcn_mfma_f32_16x16x32_bf16(a_h, b_h, acc[t], 0, 0, 0);
      acc[t] = __builtin_amdgcn_mfma_f32_16x16x32_bf16(a_h, b_l, acc[t], 0, 0, 0);
      acc[t] = __builtin_amdgcn_mfma_f32_16x16x32_bf16(a_l, b_h, acc[t], 0, 0, 0);
    }
    __syncthreads();
  }
#pragma unroll
  for (int t = 0; t < NT; ++t) {
#pragma unroll
    for (int r = 0; r < 4; ++r) {
      int grow = row0 + wave * 16 + l4 * 4 + r;
      if (grow < M) C16[(size_t)grow * N + col0 + t * 16 + l15] = f2bf(acc[t][r]);
    }
  }
}

// ---------- fused aux head: both GEMMs via MFMA, bf16 xt input ----------
template <int C>
__global__ __launch_bounds__(256) void aux_mfma(const ushort_t* __restrict__ xt16,
                                                const float* __restrict__ Wh1,
                                                const float* __restrict__ bh1,
                                                const float* __restrict__ Wh2,
                                                const float* __restrict__ bh2,
                                                float* __restrict__ hout,
                                                float scale) {
  constexpr int KS = C / 32;
  constexpr int LDB = C + 8;
  constexpr int UNION_B = 64 * LDB * 2 * 2;
  constexpr int UNION_H = 64 * 72 * 2 * 2;
  constexpr int UNION = UNION_B > UNION_H ? UNION_B : UNION_H;
  __shared__ alignas(16) char smem[9216 + UNION];
  ushort_t* w2h = (ushort_t*)smem;
  ushort_t* w2l = w2h + 32 * 72;
  ushort_t* BhS = (ushort_t*)(smem + 9216);
  ushort_t* BlS = BhS + 64 * LDB;
  ushort_t* hidh = (ushort_t*)(smem + 9216);
  ushort_t* hidl = hidh + 64 * 72;

  int tid = threadIdx.x;
  for (int i = tid; i < C * 64; i += 256) {
    int k = i >> 6, col = i & 63;
    float v = Wh1[i];
    unsigned short h = f2bf(v);
    BhS[col * LDB + k] = h;
    BlS[col * LDB + k] = f2bf(v - bf2f(h));
  }
  for (int i = tid; i < 64 * 32; i += 256) {
    int k = i >> 5, col = i & 31;
    float v = Wh2[i];
    unsigned short h = f2bf(v);
    w2h[col * 72 + k] = h;
    w2l[col * 72 + k] = f2bf(v - bf2f(h));
  }
  __syncthreads();

  int w = tid >> 6, lane = tid & 63, l15 = lane & 15, l4 = lane >> 4;
  int gr = blockIdx.x * 64 + w * 16 + l15;
  const int M2 = 2 * NN;

  f32x4 acc[4];
#pragma unroll
  for (int t = 0; t < 4; ++t) acc[t] = (f32x4){0.f, 0.f, 0.f, 0.f};

#pragma unroll
  for (int ks = 0; ks < KS; ++ks) {
    bf16x8 ah;
    if (gr < M2) {
      ah = *(const bf16x8*)(xt16 + (size_t)gr * C + ks * 32 + l4 * 8);
    } else {
      ah = (bf16x8){0, 0, 0, 0, 0, 0, 0, 0};
    }
#pragma unroll
    for (int t = 0; t < 4; ++t) {
      bf16x8 b_h = *(const bf16x8*)&BhS[(t * 16 + l15) * LDB + ks * 32 + l4 * 8];
      bf16x8 b_l = *(const bf16x8*)&BlS[(t * 16 + l15) * LDB + ks * 32 + l4 * 8];
      acc[t] = __builtin_amdgcn_mfma_f32_16x16x32_bf16(ah, b_h, acc[t], 0, 0, 0);
      acc[t] = __builtin_amdgcn_mfma_f32_16x16x32_bf16(ah, b_l, acc[t], 0, 0, 0);
    }
  }
  __syncthreads();
#pragma unroll
  for (int t = 0; t < 4; ++t) {
    float bb = bh1[t * 16 + l15];
#pragma unroll
    for (int r = 0; r < 4; ++r) {
      float h = eluf(acc[t][r] + bb);
      unsigned short hh = f2bf(h);
      int row = w * 16 + l4 * 4 + r, col = t * 16 + l15;
      hidh[row * 72 + col] = hh;
      hidl[row * 72 + col] = f2bf(h - bf2f(hh));
    }
  }
  __syncthreads();
  f32x4 acc2[2];
  acc2[0] = (f32x4){0.f, 0.f, 0.f, 0.f};
  acc2[1] = acc2[0];
#pragma unroll
  for (int ks = 0; ks < 2; ++ks) {
    bf16x8 ah = *(const bf16x8*)&hidh[(w * 16 + l15) * 72 + ks * 32 + l4 * 8];
    bf16x8 al = *(const bf16x8*)&hidl[(w * 16 + l15) * 72 + ks * 32 + l4 * 8];
#pragma unroll
    for (int t2 = 0; t2 < 2; ++t2) {
      bf16x8 b_h = *(const bf16x8*)&w2h[(t2 * 16 + l15) * 72 + ks * 32 + l4 * 8];
      bf16x8 b_l = *(const bf16x8*)&w2l[(t2 * 16 + l15) * 72 + ks * 32 + l4 * 8];
      acc2[t2] = __builtin_amdgcn_mfma_f32_16x16x32_bf16(ah, b_h, acc2[t2], 0, 0, 0);
      acc2[t2] = __builtin_amdgcn_mfma_f32_16x16x32_bf16(ah, b_l, acc2[t2], 0, 0, 0);
      acc2[t2] = __builtin_amdgcn_mfma_f32_16x16x32_bf16(al, b_h, acc2[t2], 0, 0, 0);
    }
  }
#pragma unroll
  for (int t2 = 0; t2 < 2; ++t2) {
    int col = t2 * 16 + l15;
    float bb = bh2[col];
#pragma unroll
    for (int r = 0; r < 4; ++r) {
      int gr2 = blockIdx.x * 64 + w * 16 + l4 * 4 + r;
      if (gr2 < M2)
        hout[(size_t)(gr2 >> 1) * 64 + (gr2 & 1) * 32 + col] = (acc2[t2][r] + bb) * scale;
    }
  }
}

// ---------- CSR build ----------
__global__ __launch_bounds__(256) void hist_kernel(const int* __restrict__ ei,
                                                   int* __restrict__ cnt) {
  int e = blockIdx.x * 256 + threadIdx.x;
  if (e >= EPN) return;
  int d = (e < EE) ? ei[EE + e] : e - EE;
  atomicAdd(&cnt[d], 1);
}

__global__ __launch_bounds__(1024) void scan_blocks(const int* __restrict__ cnt,
                                                    int* __restrict__ tmp,
                                                    int* __restrict__ bsum) {
  __shared__ int lds[1024];
  int t = threadIdx.x, idx = blockIdx.x * 1024 + t;
  int v = (idx < NN) ? cnt[idx] : 0;
  lds[t] = v;
  __syncthreads();
  for (int off = 1; off < 1024; off <<= 1) {
    int add = (t >= off) ? lds[t - off] : 0;
    __syncthreads();
    lds[t] += add;
    __syncthreads();
  }
  if (idx < NN) tmp[idx] = lds[t];
  if (t == 1023) bsum[blockIdx.x] = lds[t];
}

__global__ __launch_bounds__(64) void scan_bsum(int* __restrict__ bsum, int nb) {
  int t = threadIdx.x;
  int v = (t < nb) ? bsum[t] : 0;
#pragma unroll
  for (int off = 1; off < 64; off <<= 1) {
    int u = __shfl_up(v, off);
    if (t >= off) v += u;
  }
  if (t < nb) bsum[t] = v;
}

__global__ __launch_bounds__(256) void scan_final(const int* __restrict__ cnt,
                                                  const int* __restrict__ tmp,
                                                  const int* __restrict__ bsum,
                                                  int* __restrict__ rowptr,
                                                  int* __restrict__ fill) {
  int idx = blockIdx.x * 256 + threadIdx.x;
  if (idx >= NN) return;
  int b = idx >> 10;
  int off = (b > 0) ? bsum[b - 1] : 0;
  int inc = tmp[idx] + off;
  rowptr[idx + 1] = inc;
  fill[idx] = inc - cnt[idx];
  if (idx == 0) rowptr[0] = 0;
}

__global__ __launch_bounds__(256) void scatter_kernel(const int* __restrict__ ei,
                                                      int* __restrict__ fill,
                                                      int* __restrict__ eids,
                                                      int* __restrict__ srcs) {
  int e = blockIdx.x * 256 + threadIdx.x;
  if (e >= EPN) return;
  int d, s;
  if (e < EE) { d = ei[EE + e]; s = ei[e]; } else { d = s = e - EE; }
  int pos = atomicAdd(&fill[d], 1);
  eids[pos] = e;
  srcs[pos] = s;
}

// ---------- layer-1 GAT: edge-pair waves, PER-HEAD softmax, defer-max, fused LN+ELU ----------
__global__ __launch_bounds__(256) void gat256_fused(const ushort_t* __restrict__ xt16,
                                                    const int* __restrict__ srcs,
                                                    const int* __restrict__ rowptr,
                                                    float* __restrict__ outb,
                                                    const float* __restrict__ g,
                                                    const float* __restrict__ b) {
  int node = (int)((blockIdx.x * (size_t)blockDim.x + threadIdx.x) >> 6);
  int lane = threadIdx.x & 63;
  if (node >= NN) return;
  int l32 = lane & 31, half = lane >> 5;
  int start = rowptr[node], end = rowptr[node + 1];
  float dv[8];
  unpack8(*(const uint4*)(xt16 + (size_t)node * 256 + l32 * 8), dv);
  float m = -3e38f, s_h = 0.f;
  float acc[8] = {0.f, 0.f, 0.f, 0.f, 0.f, 0.f, 0.f, 0.f};

  int i = start;
  for (; i + 8 <= end; i += 8) {
    int sj[4];
    float sv[4][8];
    float p[4];
#pragma unroll
    for (int q = 0; q < 4; ++q) sj[q] = srcs[i + q * 2 + half];
#pragma unroll
    for (int q = 0; q < 4; ++q)
      unpack8(*(const uint4*)(xt16 + (size_t)sj[q] * 256 + l32 * 8), sv[q]);
#pragma unroll
    for (int q = 0; q < 4; ++q) {
      float p_ = 0.f;
#pragma unroll
      for (int k = 0; k < 8; ++k) p_ = fmaf(sv[q][k], dv[k], p_);
      p_ += __shfl_xor(p_, 1); p_ += __shfl_xor(p_, 2);
      p_ += __shfl_xor(p_, 4); p_ += __shfl_xor(p_, 8);
      p[q] = p_ * 0.08838834764831843f;  // 1/sqrt(128)
    }
    float pm = fmaxf(fmaxf(p[0], p[1]), fmaxf(p[2], p[3]));
    if (__any(pm > m + 8.f)) {
#pragma unroll
      for (int q = 0; q < 4; ++q) {
        float pb = fmaxf(p[q], __shfl_xor(p[q], 32));
        float mn = fmaxf(m, pb);
        float scf = __expf(m - mn), w = __expf(p[q] - mn);
        s_h = s_h * scf + w;
#pragma unroll
        for (int k = 0; k < 8; ++k) acc[k] = fmaf(w, sv[q][k], acc[k] * scf);
        m = mn;
      }
    } else {
#pragma unroll
      for (int q = 0; q < 4; ++q) {
        float w = __expf(p[q] - m);
        s_h += w;
#pragma unroll
        for (int k = 0; k < 8; ++k) acc[k] = fmaf(w, sv[q][k], acc[k]);
      }
    }
  }
  for (; i < end; i += 2) {
    bool valid = (i + half) < end;
    int sj = srcs[valid ? i + half : i];
    float sv[8];
    unpack8(*(const uint4*)(xt16 + (size_t)sj * 256 + l32 * 8), sv);
    float p_ = 0.f;
#pragma unroll
    for (int k = 0; k < 8; ++k) p_ = fmaf(sv[k], dv[k], p_);
    p_ += __shfl_xor(p_, 1); p_ += __shfl_xor(p_, 2);
    p_ += __shfl_xor(p_, 4); p_ += __shfl_xor(p_, 8);
    p_ *= 0.08838834764831843f;
    if (!valid) p_ = -3e38f;
    float pb = fmaxf(p_, __shfl_xor(p_, 32));
    float mn = fmaxf(m, pb);
    float scf = __expf(m - mn);
    float w = valid ? __expf(p_ - mn) : 0.f;
    s_h = s_h * scf + w;
#pragma unroll
    for (int k = 0; k < 8; ++k) acc[k] = fmaf(w, sv[k], acc[k] * scf);
    m = mn;
  }
  float s = s_h + __shfl_xor(s_h, 32);
#pragma unroll
  for (int k = 0; k < 8; ++k) acc[k] += __shfl_xor(acc[k], 32);
  float inv = 1.f / (s + 1e-16f);
  float v[8];
#pragma unroll
  for (int k = 0; k < 8; ++k) v[k] = acc[k] * inv;
  float sum = 0.f;
#pragma unroll
  for (int k = 0; k < 8; ++k) sum += v[k];
  sum += __shfl_xor(sum, 1); sum += __shfl_xor(sum, 2); sum += __shfl_xor(sum, 4);
  sum += __shfl_xor(sum, 8); sum += __shfl_xor(sum, 16);
  float mean = sum * (1.f / 256.f);
  float q = 0.f;
#pragma unroll
  for (int k = 0; k < 8; ++k) { v[k] -= mean; q = fmaf(v[k], v[k], q); }
  q += __shfl_xor(q, 1); q += __shfl_xor(q, 2); q += __shfl_xor(q, 4);
  q += __shfl_xor(q, 8); q += __shfl_xor(q, 16);
  float rstd = rsqrtf(q * (1.f / 256.f) + 1e-5f);
  if (half == 0) {
    float4 ga = *(const float4*)&g[l32 * 8], gb = *(const float4*)&g[l32 * 8 + 4];
    float4 ba = *(const float4*)&b[l32 * 8], bb = *(const float4*)&b[l32 * 8 + 4];
    float4 r0, r1;
    r0.x = eluf(v[0] * rstd * ga.x + ba.x); r0.y = eluf(v[1] * rstd * ga.y + ba.y);
    r0.z = eluf(v[2] * rstd * ga.z + ba.z); r0.w = eluf(v[3] * rstd * ga.w + ba.w);
    r1.x = eluf(v[4] * rstd * gb.x + bb.x); r1.y = eluf(v[5] * rstd * gb.y + bb.y);
    r1.z = eluf(v[6] * rstd * gb.z + bb.z); r1.w = eluf(v[7] * rstd * gb.w + bb.w);
    *(float4*)(outb + (size_t)node * 256 + l32 * 8) = r0;
    *(float4*)(outb + (size_t)node * 256 + l32 * 8 + 4) = r1;
  }
}

// ---------- transposed-batch GAT, D=64, bf16 gathers, fused epilogue, f32 out ----------
template <int MODE>
__global__ __launch_bounds__(256) void gat64_t(const ushort_t* __restrict__ xt16,
                                               const int* __restrict__ srcs,
                                               const int* __restrict__ eids,
                                               const int* __restrict__ rowptr,
                                               float* __restrict__ outf,
                                               float* __restrict__ logit_out,
                                               float* __restrict__ mbuf,
                                               float* __restrict__ sbuf,
                                               const float* __restrict__ g,
                                               const float* __restrict__ b) {
  __shared__ alignas(16) float wbuf[4][64];
  int wv = threadIdx.x >> 6;
  int node = (int)((blockIdx.x * (size_t)blockDim.x + threadIdx.x) >> 6);
  int lane = threadIdx.x & 63;
  if (node >= NN) return;
  int l32 = lane & 31, half = lane >> 5;
  int start = rowptr[node], end = rowptr[node + 1];
  float dv[32];
  {
    const ushort_t* dp = xt16 + (size_t)node * 64 + half * 32;
    unpack8(*(const uint4*)(dp), dv);
    unpack8(*(const uint4*)(dp + 8), dv + 8);
    unpack8(*(const uint4*)(dp + 16), dv + 16);
    unpack8(*(const uint4*)(dp + 24), dv + 24);
  }
  float m = -3e38f, s = 0.f, acc = 0.f;

  for (int base = start; base < end; base += 32) {
    int cnt = end - base;
    cnt = cnt > 32 ? 32 : cnt;
    int sidx = srcs[base + (l32 < cnt ? l32 : 0)];
    float sv[32];
    {
      const ushort_t* sp = xt16 + (size_t)sidx * 64 + half * 32;
      unpack8(*(const uint4*)(sp), sv);
      unpack8(*(const uint4*)(sp + 8), sv + 8);
      unpack8(*(const uint4*)(sp + 16), sv + 16);
      unpack8(*(const uint4*)(sp + 24), sv + 24);
    }
    float p = 0.f;
#pragma unroll
    for (int k = 0; k < 32; ++k) p = fmaf(sv[k], dv[k], p);
    p *= 0.17677669529663687f;  // 1/sqrt(32)
    if (MODE == 1) {
      if (l32 < cnt) logit_out[(size_t)eids[base + l32] * 2 + half] = p;
    }
    if (l32 >= cnt) p = -3e38f;
    float bm = p;
    bm = fmaxf(bm, __shfl_xor(bm, 1));
    bm = fmaxf(bm, __shfl_xor(bm, 2));
    bm = fmaxf(bm, __shfl_xor(bm, 4));
    bm = fmaxf(bm, __shfl_xor(bm, 8));
    bm = fmaxf(bm, __shfl_xor(bm, 16));
    float mn = fmaxf(m, bm);
    float scf = __expf(m - mn);
    float w = (l32 < cnt) ? __expf(p - mn) : 0.f;
    wbuf[wv][(half << 5) + l32] = w;
    float bs = w;
    bs += __shfl_xor(bs, 1);
    bs += __shfl_xor(bs, 2);
    bs += __shfl_xor(bs, 4);
    bs += __shfl_xor(bs, 8);
    bs += __shfl_xor(bs, 16);
    s = s * scf + bs;
    acc *= scf;
    m = mn;
    int nb4 = cnt & ~3;
    const float* wp = &wbuf[wv][(half << 5)];
    for (int e = 0; e < nb4; e += 4) {
      float4 w4 = *(const float4*)(wp + e);
      int s0 = srcs[base + e + 0];
      int s1 = srcs[base + e + 1];
      int s2 = srcs[base + e + 2];
      int s3 = srcs[base + e + 3];
      acc = fmaf(w4.x, bf2f(xt16[(size_t)s0 * 64 + lane]), acc);
      acc = fmaf(w4.y, bf2f(xt16[(size_t)s1 * 64 + lane]), acc);
      acc = fmaf(w4.z, bf2f(xt16[(size_t)s2 * 64 + lane]), acc);
      acc = fmaf(w4.w, bf2f(xt16[(size_t)s3 * 64 + lane]), acc);
    }
    for (int e = nb4; e < cnt; ++e) {
      float wq = wp[e];
      int sj = srcs[base + e];
      acc = fmaf(wq, bf2f(xt16[(size_t)sj * 64 + lane]), acc);
    }
  }
  float inv = 1.f / (s + 1e-16f);
  float v = acc * inv;
  if (MODE == 0) {
    float sum = v;
#pragma unroll
    for (int o = 1; o < 64; o <<= 1) sum += __shfl_xor(sum, o);
    float mean = sum * (1.f / 64.f);
    float dvv = v - mean;
    float q = dvv * dvv;
#pragma unroll
    for (int o = 1; o < 64; o <<= 1) q += __shfl_xor(q, o);
    float rstd = rsqrtf(q * (1.f / 64.f) + 1e-5f);
    outf[(size_t)node * 64 + lane] = eluf(dvv * rstd * g[lane] + b[lane]);
  } else {
    if (l32 == 0) {
      mbuf[(size_t)node * 2 + half] = m;
      sbuf[(size_t)node * 2 + half] = s;
    }
    float t = __shfl_xor(v, 32);
    float y = 0.5f * (v + t);
    float sum = y;
#pragma unroll
    for (int o = 1; o < 32; o <<= 1) sum += __shfl_xor(sum, o);
    float mean = sum * (1.f / 32.f);
    float dy = y - mean;
    float q = dy * dy;
#pragma unroll
    for (int o = 1; o < 32; o <<= 1) q += __shfl_xor(q, o);
    float rstd = rsqrtf(q * (1.f / 32.f) + 1e-5f);
    if (half == 0) outf[(size_t)node * 32 + l32] = dy * rstd * g[l32] + b[l32];
  }
}

// ---------- alpha fix-up ----------
__global__ __launch_bounds__(256) void alpha_fix(float* __restrict__ al,
                                                 const int* __restrict__ ei,
                                                 const float* __restrict__ mbuf,
                                                 const float* __restrict__ sbuf) {
  size_t i = blockIdx.x * (size_t)blockDim.x + threadIdx.x;
  if (i >= (size_t)EPN * 2) return;
  int e = (int)(i >> 1), h = (int)(i & 1);
  int d = (e < EE) ? ei[EE + e] : e - EE;
  al[i] = expf(al[i] - mbuf[(size_t)d * 2 + h]) / (sbuf[(size_t)d * 2 + h] + 1e-16f);
}

extern "C" void kernel_launch(void* const* d_in, const int* in_sizes, int n_in,
                              void* d_out, int out_size, void* d_ws, size_t ws_size,
                              hipStream_t stream) {
  const float* x    = (const float*)d_in[0];
  const int*   ei   = (const int*)d_in[1];
  const float* W1   = (const float*)d_in[2];
  const float* Wh1a = (const float*)d_in[3];
  const float* bh1a = (const float*)d_in[4];
  const float* Wh2a = (const float*)d_in[5];
  const float* bh2a = (const float*)d_in[6];
  const float* g1   = (const float*)d_in[7];
  const float* b1   = (const float*)d_in[8];
  const float* W2   = (const float*)d_in[9];
  const float* Wh1b = (const float*)d_in[10];
  const float* bh1b = (const float*)d_in[11];
  const float* Wh2b = (const float*)d_in[12];
  const float* bh2b = (const float*)d_in[13];
  const float* g2   = (const float*)d_in[14];
  const float* b2   = (const float*)d_in[15];
  const float* W3   = (const float*)d_in[16];
  const float* Wh1c = (const float*)d_in[17];
  const float* bh1c = (const float*)d_in[18];
  const float* Wh2c = (const float*)d_in[19];
  const float* bh2c = (const float*)d_in[20];
  const float* g3   = (const float*)d_in[21];
  const float* b3   = (const float*)d_in[22];

  float* out  = (float*)d_out;
  float* o_x3 = out;                           // N*32
  float* o_h1 = out + (size_t)NN * 32;         // N*64
  float* o_h2 = o_h1 + (size_t)NN * 64;        // N*64
  float* o_h3 = o_h2 + (size_t)NN * 64;        // N*64
  float* o_al = o_h3 + (size_t)NN * 64;        // EPN*2 (logits then alpha)

  float* ws  = (float*)d_ws;
  float* A   = ws;                             // N*256 f32 slot (bf16 xt)
  float* Bb  = ws + (size_t)NN * 256;          // N*256 f32 (x1/x2)
  int* cnt    = (int*)(Bb + (size_t)NN * 256); // NN
  int* rowptr = cnt + NN;                      // NN+1
  int* fill   = rowptr + NN + 1;               // NN
  int* eids   = fill + NN;                     // EPN
  int* srcs   = eids + EPN;                    // EPN
  int* tmp    = srcs + EPN;                    // NN
  int* bsum   = tmp + NN;                      // 64
  float* mbuf = (float*)(bsum + 64);           // NN*2
  float* sbuf = mbuf + (size_t)NN * 2;         // NN*2
  ushort_t* W1c = (ushort_t*)(sbuf + (size_t)NN * 2);  // 256*1024 ushorts
  ushort_t* A16 = (ushort_t*)A;                // xt buffers (bf16)

  dim3 blk(256);
  int gEdges = (EPN + 255) / 256;
  int gNodeW = (NN * 64 + 255) / 256;
  int gRows = (NN + 63) / 64;
  int gRows128 = (NN + 127) / 128;
  int gPairs = (int)(((size_t)EPN * 2 + 255) / 256);
  int gAux = (2 * NN + 63) / 64;
  int nbScan = (NN + 1023) / 1024;

  // ---------------- CSR by dst + W1 preconversion ----------------
  conv_w1<<<1024, blk, 0, stream>>>(W1, W1c);
  hipMemsetAsync(cnt, 0, (size_t)NN * 4, stream);
  hist_kernel<<<gEdges, blk, 0, stream>>>(ei, cnt);
  scan_blocks<<<nbScan, 1024, 0, stream>>>(cnt, tmp, bsum);
  scan_bsum<<<1, 64, 0, stream>>>(bsum, nbScan);
  scan_final<<<(NN + 255) / 256, blk, 0, stream>>>(cnt, tmp, bsum, rowptr, fill);
  scatter_kernel<<<gEdges, blk, 0, stream>>>(ei, fill, eids, srcs);

  // ---------------- Layer 1: 512 -> 2x128 (concat) ----------------
  gemm1_mfma<<<dim3(2, gRows128), 512, 0, stream>>>(x, W1c, A16, NN);
  aux_mfma<128><<<gAux, blk, 0, stream>>>(A16, Wh1a, bh1a, Wh2a, bh2a, o_h1, 1.0f);
  gat256_fused<<<gNodeW, blk, 0, stream>>>(A16, srcs, rowptr, Bb, g1, b1);

  // ---------------- Layer 2: 256 -> 2x32 (concat) ----------------
  gemm_mfma<4><<<dim3(1, gRows), blk, 0, stream>>>(Bb, W2, A16, NN, 64, 256);
  aux_mfma<32><<<gAux, blk, 0, stream>>>(A16, Wh1b, bh1b, Wh2b, bh2b, o_h2, 0.5f);
  gat64_t<0><<<gNodeW, blk, 0, stream>>>(A16, srcs, nullptr, rowptr, Bb, nullptr,
                                         nullptr, nullptr, g2, b2);

  // ---------------- Layer 3: 64 -> 2x32 (mean) ----------------
  gemm_mfma<4><<<dim3(1, gRows), blk, 0, stream>>>(Bb, W3, A16, NN, 64, 64);
  aux_mfma<32><<<gAux, blk, 0, stream>>>(A16, Wh1c, bh1c, Wh2c, bh2c, o_h3, 1.0f);
  gat64_t<1><<<gNodeW, blk, 0, stream>>>(A16, srcs, eids, rowptr, o_x3, o_al,
                                         mbuf, sbuf, g3, b3);
  alpha_fix<<<gPairs, blk, 0, stream>>>(o_al, ei, mbuf, sbuf);
}